// Round 8
// baseline (4634.925 us; speedup 1.0000x reference)
//
#include <hip/hip_runtime.h>

typedef _Float16 h8 __attribute__((ext_vector_type(8)));
typedef float    f4 __attribute__((ext_vector_type(4)));
typedef float    f2 __attribute__((ext_vector_type(2)));

// ---------------- workspace layout (bytes) ----------------
// hbuf : [parity 2][ig 8][grp 2][row 4][unit 512] fp32-with-tag = 262,144
//        each dword: fp32 h value, 10-bit step tag in mantissa LSBs
static const unsigned long long WS_NEEDED = 262144ull;

__device__ __forceinline__ float sigm(float x)   { return 1.0f / (1.0f + __expf(-x)); }
__device__ __forceinline__ float tanh_a(float x) { return 2.0f / (1.0f + __expf(-2.0f * x)) - 1.0f; }

// tag 1023 (= expected at t=0), value = denormal -> fp16 0
__global__ __launch_bounds__(256) void k_init(unsigned* hbuf)
{
    const int idx = blockIdx.x * 256 + threadIdx.x;
    if (idx < 65536) hbuf[idx] = 0x000003FFu;
}

// ---------------- k_rec: persistent LSTM, tag protocol + row-split ping-pong ----------------
// 64 blocks = 8 batch-groups (ig) x 8 unit-groups (jg: 64 units). Each team's
// 8 rows split into groups A(0-3)/B(4-7); blocks alternate sub-steps so group
// g's h(t-1) is consumed one full sub-step after publish -> MALL visibility
// (the R7 residue) hides under the other group's compute. Wave-local retry
// (no block barriers while polling). LDS rows padded to 1056/544 B so both
// staging writes and b128 fragment reads are <=2-way (free) -- R7's 4.2e7
// conflicts came from 16-way staging writes.
__global__ __launch_bounds__(256, 1) void k_rec(
    const float* __restrict__ x,
    const float* __restrict__ Ui, const float* __restrict__ Vi, const float* __restrict__ bi,
    const float* __restrict__ Uf, const float* __restrict__ Vf, const float* __restrict__ bf,
    const float* __restrict__ Uh, const float* __restrict__ Vh, const float* __restrict__ bh,
    const float* __restrict__ Uo, const float* __restrict__ Vo, const float* __restrict__ bo,
    unsigned* hbuf)
{
    const int bx = blockIdx.x;
    const int ig = bx & 7, jg = bx >> 3;
    const int tid = threadIdx.x;
    const int w = tid >> 6, l = tid & 63;
    const int lo = l & 15, hi = l >> 4, r4 = lo & 3;
    const int unit = jg * 64 + w * 16 + lo;          // hidden unit [0,512)

    // padded row-major staging: h rows 528 halves (1056 B), x rows 272 (544 B)
    __shared__ __align__(16) _Float16 ldsH[8 * 528];   // [grp 2][row 4][...]
    __shared__ __align__(16) _Float16 ldsX[8 * 272];

    const float* Ug[4] = {Ui, Uf, Uh, Uo};
    const float* Vg[4] = {Vi, Vf, Vh, Vo};
    const float* bg[4] = {bi, bf, bh, bo};

    // ---- one-time fragment preload (fp32 -> fp16 cvt) ----
    // B-frag (16x16x32): lane holds B[k = kc*32 + hi*8 + jj][n = lo]
    h8 vfrag[4][16];
    h8 ufrag[4][8];
    float bias[4];
#pragma unroll
    for (int g = 0; g < 4; ++g) {
        bias[g] = bg[g][unit];
#pragma unroll
        for (int kc = 0; kc < 16; ++kc) {
            h8 v;
#pragma unroll
            for (int jj = 0; jj < 8; ++jj)
                v[jj] = (_Float16)Vg[g][(size_t)(kc * 32 + hi * 8 + jj) * 512 + unit];
            vfrag[g][kc] = v;
        }
#pragma unroll
        for (int kc = 0; kc < 8; ++kc) {
            h8 u;
#pragma unroll
            for (int jj = 0; jj < 8; ++jj)
                u[jj] = (_Float16)Ug[g][(size_t)(kc * 32 + hi * 8 + jj) * 512 + unit];
            ufrag[g][kc] = u;
        }
    }

    // x staging: thread handles (row, float-pair) twice: linear = {tid, 256+tid}
    const int xr0 = tid >> 7, xc0 = tid & 127;
    const int xr1 = xr0 + 2,  xc1 = xc0;

    f4 cst0 = {0.f, 0.f, 0.f, 0.f};   // cell state rows 0-3 (group A), elem d = row d
    f4 cst1 = {0.f, 0.f, 0.f, 0.f};   // group B

    // ---- prologue: stage x(t=0, grp 0) ----
    {
        const f2 a0 = *(const f2*)(x + (size_t)(ig * 8 + xr0) * 262144 + 2 * xc0);
        const f2 a1 = *(const f2*)(x + (size_t)(ig * 8 + xr1) * 262144 + 2 * xc1);
        union { _Float16 h[2]; unsigned u; } p0, p1;
        p0.h[0] = (_Float16)a0[0]; p0.h[1] = (_Float16)a0[1];
        p1.h[0] = (_Float16)a1[0]; p1.h[1] = (_Float16)a1[1];
        *(unsigned*)&ldsX[(size_t)(xr0 * 272 + 2 * xc0)] = p0.u;
        *(unsigned*)&ldsX[(size_t)(xr1 * 272 + 2 * xc1)] = p1.u;
        __syncthreads();
    }

#define SUBSTEP(G, CST)                                                                              \
  {                                                                                                  \
    const int pr = (t + 1) & 1, pw = t & 1;                                                          \
    const unsigned etag = (unsigned)((t + 1023) & 1023);                                             \
    const unsigned ptag = (unsigned)(t & 1023);                                                      \
    /* issue h loads first: wave w stages row w of group G (coalesced 8B) */                         \
    const unsigned long long* hpd = (const unsigned long long*)                                      \
        (hbuf + (size_t)(((pr * 8 + ig) * 2 + (G)) * 2048 + w * 512)) + l;                           \
    unsigned long long q0 = __hip_atomic_load(hpd,       __ATOMIC_RELAXED, __HIP_MEMORY_SCOPE_AGENT);\
    unsigned long long q1 = __hip_atomic_load(hpd + 64,  __ATOMIC_RELAXED, __HIP_MEMORY_SCOPE_AGENT);\
    unsigned long long q2 = __hip_atomic_load(hpd + 128, __ATOMIC_RELAXED, __HIP_MEMORY_SCOPE_AGENT);\
    unsigned long long q3 = __hip_atomic_load(hpd + 192, __ATOMIC_RELAXED, __HIP_MEMORY_SCOPE_AGENT);\
    /* issue x loads for the NEXT sub-step (consumed from LDS then) */                               \
    const int tp = ((G) == 0) ? t : ((t < 1023) ? t + 1 : t);                                        \
    const int gp = (G) ^ 1;                                                                          \
    const f2 xv0 = *(const f2*)(x + (size_t)(ig * 8 + gp * 4 + xr0) * 262144                         \
                                  + (size_t)tp * 256 + 2 * xc0);                                     \
    const f2 xv1 = *(const f2*)(x + (size_t)(ig * 8 + gp * 4 + xr1) * 262144                         \
                                  + (size_t)tp * 256 + 2 * xc1);                                     \
    /* gate-init: bias + x_t @ U from ldsX[G] (shadow work under load flight) */                     \
    f4 acc[4];                                                                                       \
    _Pragma("unroll")                                                                                \
    for (int g = 0; g < 4; ++g) {                                                                    \
        f4 a; a[0] = bias[g]; a[1] = bias[g]; a[2] = bias[g]; a[3] = bias[g]; acc[g] = a;            \
    }                                                                                                \
    _Pragma("unroll")                                                                                \
    for (int kc = 0; kc < 8; ++kc) {                                                                 \
        const h8 xa = *(const h8*)&ldsX[(size_t)(((G) * 4 + r4) * 272 + kc * 32 + hi * 8)];          \
        acc[0] = __builtin_amdgcn_mfma_f32_16x16x32_f16(xa, ufrag[0][kc], acc[0], 0, 0, 0);          \
        acc[1] = __builtin_amdgcn_mfma_f32_16x16x32_f16(xa, ufrag[1][kc], acc[1], 0, 0, 0);          \
        acc[2] = __builtin_amdgcn_mfma_f32_16x16x32_f16(xa, ufrag[2][kc], acc[2], 0, 0, 0);          \
        acc[3] = __builtin_amdgcn_mfma_f32_16x16x32_f16(xa, ufrag[3][kc], acc[3], 0, 0, 0);          \
    }                                                                                                \
    /* wave-local tag check + retry (no block barriers while polling) */                             \
    while (true) {                                                                                   \
        unsigned e = ((unsigned)q0 ^ etag) | ((unsigned)(q0 >> 32) ^ etag);                          \
        e |= ((unsigned)q1 ^ etag) | ((unsigned)(q1 >> 32) ^ etag);                                  \
        e |= ((unsigned)q2 ^ etag) | ((unsigned)(q2 >> 32) ^ etag);                                  \
        e |= ((unsigned)q3 ^ etag) | ((unsigned)(q3 >> 32) ^ etag);                                  \
        if (__ballot((e & 1023u) != 0u) == 0ull) break;                                              \
        q0 = __hip_atomic_load(hpd,       __ATOMIC_RELAXED, __HIP_MEMORY_SCOPE_AGENT);               \
        q1 = __hip_atomic_load(hpd + 64,  __ATOMIC_RELAXED, __HIP_MEMORY_SCOPE_AGENT);               \
        q2 = __hip_atomic_load(hpd + 128, __ATOMIC_RELAXED, __HIP_MEMORY_SCOPE_AGENT);               \
        q3 = __hip_atomic_load(hpd + 192, __ATOMIC_RELAXED, __HIP_MEMORY_SCOPE_AGENT);               \
    }                                                                                                \
    /* stage h -> ldsH[G] row w (fp16 pairs; <=2-way banks) */                                       \
    {                                                                                                \
        union { _Float16 h[2]; unsigned u; } p;                                                      \
        p.h[0] = (_Float16)__uint_as_float((unsigned)q0);                                            \
        p.h[1] = (_Float16)__uint_as_float((unsigned)(q0 >> 32));                                    \
        *(unsigned*)&ldsH[(size_t)(((G) * 4 + w) * 528 + 2 * l)] = p.u;                              \
        p.h[0] = (_Float16)__uint_as_float((unsigned)q1);                                            \
        p.h[1] = (_Float16)__uint_as_float((unsigned)(q1 >> 32));                                    \
        *(unsigned*)&ldsH[(size_t)(((G) * 4 + w) * 528 + 2 * (l + 64))] = p.u;                       \
        p.h[0] = (_Float16)__uint_as_float((unsigned)q2);                                            \
        p.h[1] = (_Float16)__uint_as_float((unsigned)(q2 >> 32));                                    \
        *(unsigned*)&ldsH[(size_t)(((G) * 4 + w) * 528 + 2 * (l + 128))] = p.u;                      \
        p.h[0] = (_Float16)__uint_as_float((unsigned)q3);                                            \
        p.h[1] = (_Float16)__uint_as_float((unsigned)(q3 >> 32));                                    \
        *(unsigned*)&ldsH[(size_t)(((G) * 4 + w) * 528 + 2 * (l + 192))] = p.u;                      \
    }                                                                                                \
    /* stage x_next -> ldsX[gp] */                                                                   \
    {                                                                                                \
        union { _Float16 h[2]; unsigned u; } p0, p1;                                                 \
        p0.h[0] = (_Float16)xv0[0]; p0.h[1] = (_Float16)xv0[1];                                      \
        p1.h[0] = (_Float16)xv1[0]; p1.h[1] = (_Float16)xv1[1];                                      \
        *(unsigned*)&ldsX[(size_t)((gp * 4 + xr0) * 272 + 2 * xc0)] = p0.u;                          \
        *(unsigned*)&ldsX[(size_t)((gp * 4 + xr1) * 272 + 2 * xc1)] = p1.u;                          \
    }                                                                                                \
    __syncthreads();                                                                                 \
    /* h_{t-1} @ V from ldsH[G] */                                                                   \
    _Pragma("unroll")                                                                                \
    for (int kc = 0; kc < 16; ++kc) {                                                                \
        const h8 a = *(const h8*)&ldsH[(size_t)(((G) * 4 + r4) * 528 + kc * 32 + hi * 8)];           \
        acc[0] = __builtin_amdgcn_mfma_f32_16x16x32_f16(a, vfrag[0][kc], acc[0], 0, 0, 0);           \
        acc[1] = __builtin_amdgcn_mfma_f32_16x16x32_f16(a, vfrag[1][kc], acc[1], 0, 0, 0);           \
        acc[2] = __builtin_amdgcn_mfma_f32_16x16x32_f16(a, vfrag[2][kc], acc[2], 0, 0, 0);           \
        acc[3] = __builtin_amdgcn_mfma_f32_16x16x32_f16(a, vfrag[3][kc], acc[3], 0, 0, 0);           \
    }                                                                                                \
    /* elementwise (elem d == row d, duplicated across hi) + tagged publish */                       \
    f4 hvv;                                                                                          \
    _Pragma("unroll")                                                                                \
    for (int d = 0; d < 4; ++d) {                                                                    \
        const float iv = sigm(acc[0][d]);                                                            \
        const float fv = sigm(acc[1][d]);                                                            \
        const float gv = tanh_a(acc[2][d]);                                                          \
        const float ov = sigm(acc[3][d]);                                                            \
        const float c = fv * (CST)[d] + iv * gv;                                                     \
        (CST)[d] = c;                                                                                \
        hvv[d] = ov * tanh_a(c);                                                                     \
    }                                                                                                \
    const float hsel = (hi == 0) ? hvv[0] : (hi == 1) ? hvv[1] : (hi == 2) ? hvv[2] : hvv[3];        \
    const unsigned pv = (__float_as_uint(hsel) & 0xFFFFFC00u) | ptag;                                \
    __hip_atomic_store(hbuf + (size_t)(((pw * 8 + ig) * 2 + (G)) * 2048 + hi * 512 + unit),          \
                       pv, __ATOMIC_RELAXED, __HIP_MEMORY_SCOPE_AGENT);                              \
  }

#pragma unroll 1
    for (int t = 0; t < 1024; ++t) {
        SUBSTEP(0, cst0)
        SUBSTEP(1, cst1)
    }
#undef SUBSTEP
}

// ---------------- k_fc: out[b] = h_last[b,:] . fc_w + fc_b ----------------
__global__ __launch_bounds__(64) void k_fc(
    const unsigned* __restrict__ hbuf, const float* __restrict__ fcw,
    const float* __restrict__ fcb, float* __restrict__ out)
{
    const int b = blockIdx.x, l = threadIdx.x;
    // t=1023 -> parity 1; ig = b>>3, team row r = b&7 -> grp r>>2, row r&3
    const int ig = b >> 3, r = b & 7;
    const unsigned* h = hbuf + (size_t)((((8 + ig) * 2) + (r >> 2)) * 2048 + (r & 3) * 512);
    float s = 0.f;
#pragma unroll
    for (int k = 0; k < 8; ++k)
        s += __uint_as_float(h[l + k * 64] & 0xFFFFFC00u) * fcw[l + k * 64];
    for (int off = 32; off > 0; off >>= 1) s += __shfl_down(s, off, 64);
    if (l == 0) out[b] = s + fcb[0];
}

__global__ __launch_bounds__(64) void k_sentinel(float* out)
{
    out[threadIdx.x] = -777777.0f;   // signature: ws_size too small
}

extern "C" void kernel_launch(void* const* d_in, const int* in_sizes, int n_in,
                              void* d_out, int out_size, void* d_ws, size_t ws_size,
                              hipStream_t stream)
{
    const float* x   = (const float*)d_in[0];
    const float* Ui  = (const float*)d_in[1];
    const float* Vi  = (const float*)d_in[2];
    const float* bi  = (const float*)d_in[3];
    const float* Uf  = (const float*)d_in[4];
    const float* Vf  = (const float*)d_in[5];
    const float* bf  = (const float*)d_in[6];
    const float* Uh  = (const float*)d_in[7];
    const float* Vh  = (const float*)d_in[8];
    const float* bh  = (const float*)d_in[9];
    const float* Uo  = (const float*)d_in[10];
    const float* Vo  = (const float*)d_in[11];
    const float* bo  = (const float*)d_in[12];
    const float* fcw = (const float*)d_in[13];
    const float* fcb = (const float*)d_in[14];
    float* out = (float*)d_out;

    if (ws_size < WS_NEEDED) {
        k_sentinel<<<1, 64, 0, stream>>>(out);
        return;
    }

    unsigned* hbuf = (unsigned*)d_ws;

    k_init<<<256, 256, 0, stream>>>(hbuf);
    k_rec <<<64,  256, 0, stream>>>(x, Ui, Vi, bi, Uf, Vf, bf, Uh, Vh, bh,
                                    Uo, Vo, bo, hbuf);
    k_fc  <<<64,   64, 0, stream>>>(hbuf, fcw, fcb, out);
}